// Round 18
// baseline (160.304 us; speedup 1.0000x reference)
//
#include <hip/hip_runtime.h>
#include <hip/hip_bf16.h>

typedef unsigned short u16;
typedef unsigned int u32;
typedef __attribute__((ext_vector_type(8))) short bf16x8;   // 8 bf16 = 4 VGPR (MFMA A/B frag)
typedef __attribute__((ext_vector_type(4))) float f32x4;    // MFMA C/D frag
typedef __attribute__((ext_vector_type(8))) unsigned short u16x8;
typedef __attribute__((ext_vector_type(2))) unsigned int u32x2;

#define T_ 2048
#define H_ 8
#define BH_ 32
#define M_ 8192
#define SCALE_QK 0.29730177875068026f   // 128^(-0.25), folded into Wq and Wk
#define LOG2E 1.4426950408889634f       // extra factor on Wq -> softmax in exp2 domain

__device__ __forceinline__ u16 f2bf(float f) {
  union { __hip_bfloat16 h; u16 u; } cv; cv.h = __float2bfloat16(f); return cv.u;
}
__device__ __forceinline__ float bf2f(u16 u) {
  union { u16 u; __hip_bfloat16 h; } cv; cv.u = u; return __bfloat162float(cv.h);
}

// K image block (bh,kt): 64x128 tile, elem(kr,d) at kr*128 + (((d>>3)^(kr&15))<<3) + (d&7)
// V image block (bh,kt): 128x64 tile, elem(d,kk) at d*64  + (((kk>>3)^(d&7))<<3)  + (kk&7)
// Both are verbatim images of the flash kernel's swizzled LDS tiles.
// (R16 lesson: V MUST be LDS-staged — direct per-fragment global reads
// overfetch HBM 8.7x; LDS staging is the coalescing mechanism.)

// ---------------------------------------------------------------------------
// Kernel 1: prep — x -> bf16; Wq/Wk/Wv -> WT[n][k] bf16 (scale folded for q,k;
// Wq additionally scaled by log2e so flash softmax runs in exp2 domain);
// Wu -> WuT[n][k] bf16.
// ---------------------------------------------------------------------------
__global__ __launch_bounds__(256)
void prep_kernel(const float* __restrict__ x, const float* __restrict__ Wq,
                 const float* __restrict__ Wk, const float* __restrict__ Wv,
                 const float* __restrict__ Wu,
                 u16* __restrict__ xb, u16* __restrict__ WT, u16* __restrict__ WuT)
{
  int i = blockIdx.x * 256 + threadIdx.x;
  if (i < M_ * 128) { xb[i] = f2bf(x[i]); return; }
  int j = i - M_ * 128;
  if (j < 3072 * 128) {
    int n = j >> 7, k = j & 127;
    float w;
    if (n < 1024)      w = Wq[k * 1024 + n] * (SCALE_QK * LOG2E);
    else if (n < 2048) w = Wk[k * 1024 + (n - 1024)] * SCALE_QK;
    else               w = Wv[k * 1024 + (n - 2048)];
    WT[j] = f2bf(w);
    return;
  }
  int u = j - 3072 * 128;
  if (u < 128 * 1024) {
    int n = u >> 10, k = u & 1023;
    WuT[u] = f2bf(Wu[k * 128 + n]);
  }
}

// ---------------------------------------------------------------------------
// Kernel 2: maskprep — pack mask row q into 64 u32 bitwords (bit=mask!=0);
// degenerate rows -> deglist (atomic append); cnt0inv[q]. One wave per row.
// ---------------------------------------------------------------------------
__global__ __launch_bounds__(256)
void maskprep_kernel(const int* __restrict__ mask, u32* __restrict__ mbits,
                     u32* __restrict__ deglist, u32* __restrict__ degcount,
                     float* __restrict__ cnt0inv)
{
  int wave = threadIdx.x >> 6, lane = threadIdx.x & 63;
  int q = blockIdx.x * 4 + wave;
  const int* row = mask + (long)q * 2048;
  unsigned long long anyvis = 0ull;
  int cnt1 = 0;
  for (int it = 0; it < 32; ++it) {
    int k = it * 64 + lane;
    unsigned long long bal = __ballot(row[k] != 0);
    if (lane == 0) {
      mbits[q * 64 + it * 2]     = (u32)bal;
      mbits[q * 64 + it * 2 + 1] = (u32)(bal >> 32);
    }
    cnt1 += __popcll(bal);
    int lim = q - it * 64;                      // visible lane offsets: 0..lim
    if (lim >= 63)      anyvis |= bal;
    else if (lim >= 0)  anyvis |= (bal & ((2ull << lim) - 1ull));
  }
  if (lane == 0) {
    int c0 = 2048 - cnt1;
    cnt0inv[q] = (c0 > 0) ? 1.0f / (float)c0 : 0.0f;
    if (anyvis == 0ull) {
      u32 slot = atomicAdd(degcount, 1u);
      deglist[slot] = (u32)q;
    }
  }
}

// ---------------------------------------------------------------------------
// Kernel 3: QKV projection GEMM. 128x128 tile, K=128, 4 waves, 16x16x32 MFMA.
// All epilogues go through LDS staging -> coalesced u16x8 global stores
// (no scalar global scatter). Q row-major; K,V as swizzled image blocks.
// ---------------------------------------------------------------------------
__global__ __launch_bounds__(256)
void qkv_kernel(const u16* __restrict__ xb, const u16* __restrict__ WT,
                u16* __restrict__ Qb, u16* __restrict__ Kimg, u16* __restrict__ Vimg)
{
  __shared__ __align__(16) u16 As[128 * 128];
  __shared__ __align__(16) u16 Bs[128 * 128];
  const int tid = threadIdx.x;
  const int n0 = blockIdx.x * 128;    // over concat [Wq|Wk|Wv] = 3072 cols
  const int m0 = blockIdx.y * 128;
#pragma unroll
  for (int i = 0; i < 8; ++i) {
    int c = tid + 256 * i;            // 2048 chunks of 8 elems
    int row = c >> 4, d0 = (c & 15) * 8;
    int soff = row * 128 + ((((d0 >> 3)) ^ (row & 15)) << 3);
    *(u16x8*)(&As[soff]) = *(const u16x8*)(&xb[(m0 + row) * 128 + d0]);
    *(u16x8*)(&Bs[soff]) = *(const u16x8*)(&WT[(n0 + row) * 128 + d0]);
  }
  __syncthreads();
  const int wave = tid >> 6, lane = tid & 63;
  const int lr = lane & 15, lg = lane >> 4;
  const int wm = (wave >> 1) * 64, wn = (wave & 1) * 64;
  f32x4 acc[4][4];
#pragma unroll
  for (int a = 0; a < 4; ++a)
#pragma unroll
    for (int b = 0; b < 4; ++b) acc[a][b] = (f32x4){0.f, 0.f, 0.f, 0.f};
#pragma unroll
  for (int ks = 0; ks < 4; ++ks) {
    bf16x8 af[4], bf[4];
#pragma unroll
    for (int mt = 0; mt < 4; ++mt) {
      int row = wm + mt * 16 + lr, chunk = lg + ks * 4;
      af[mt] = *(const bf16x8*)(&As[row * 128 + ((chunk ^ (row & 15)) << 3)]);
    }
#pragma unroll
    for (int nt = 0; nt < 4; ++nt) {
      int row = wn + nt * 16 + lr, chunk = lg + ks * 4;
      bf[nt] = *(const bf16x8*)(&Bs[row * 128 + ((chunk ^ (row & 15)) << 3)]);
    }
#pragma unroll
    for (int mt = 0; mt < 4; ++mt)
#pragma unroll
      for (int nt = 0; nt < 4; ++nt)
        acc[mt][nt] = __builtin_amdgcn_mfma_f32_16x16x32_bf16(af[mt], bf[nt], acc[mt][nt], 0, 0, 0);
  }
  const int mat = n0 >> 10;
  const int hh = (n0 & 1023) >> 7;
  const int bb = m0 >> 11;
  const long bhb = (long)(bb * H_ + hh);
  __syncthreads();                       // done reading As/Bs; reuse As
  if (mat != 2) {
    // stage C tile [tl][d] (chunk-swizzled), then vectorized stores
#pragma unroll
    for (int mt = 0; mt < 4; ++mt)
#pragma unroll
      for (int nt = 0; nt < 4; ++nt)
#pragma unroll
        for (int r = 0; r < 4; ++r) {
          int tl = wm + mt * 16 + lg * 4 + r;
          int d  = wn + nt * 16 + lr;
          As[tl * 128 + ((((d >> 3)) ^ (tl & 15)) << 3) + (d & 7)] = f2bf(acc[mt][nt][r]);
        }
    __syncthreads();
    if (mat == 0) {
#pragma unroll
      for (int i = 0; i < 8; ++i) {
        int c = tid + 256 * i;
        int row = c >> 4, d0 = (c & 15) * 8;
        u16x8 v = *(const u16x8*)(&As[row * 128 + ((((d0 >> 3)) ^ (row & 15)) << 3)]);
        *(u16x8*)(&Qb[(bhb * T_ + ((m0 + row) & 2047)) * 128 + d0]) = v;
      }
    } else {
#pragma unroll
      for (int i = 0; i < 8; ++i) {
        int c = tid + 256 * i;
        int row = c >> 4, d0 = (c & 15) * 8;
        u16x8 v = *(const u16x8*)(&As[row * 128 + ((((d0 >> 3)) ^ (row & 15)) << 3)]);
        int t = (m0 + row) & 2047;
        int kt = t >> 6, kr = t & 63;
        *(u16x8*)(&Kimg[(bhb * 32 + kt) * 8192 + kr * 128 + ((((d0 >> 3)) ^ (kr & 15)) << 3)]) = v;
      }
    }
  } else {
    // transpose V tile in LDS (reuse As), then u16x8 stores into V image blocks
    u16* TT = As;
#pragma unroll
    for (int mt = 0; mt < 4; ++mt)
#pragma unroll
      for (int nt = 0; nt < 4; ++nt)
#pragma unroll
        for (int r = 0; r < 4; ++r) {
          int tl = wm + mt * 16 + lg * 4 + r;   // local t 0..127
          int d  = wn + nt * 16 + lr;
          TT[d * 128 + ((((tl >> 3)) ^ (d & 15)) << 3) + (tl & 7)] = f2bf(acc[mt][nt][r]);
        }
    __syncthreads();
    const int tg0 = m0 & 2047;
#pragma unroll
    for (int i = 0; i < 8; ++i) {
      int c = tid + 256 * i;
      int d = c >> 4, t0 = (c & 15) * 8;
      u16x8 v = *(const u16x8*)(&TT[d * 128 + ((((t0 >> 3)) ^ (d & 15)) << 3)]);
      int tg = tg0 + t0;
      int kt = tg >> 6, kk = tg & 63;
      *(u16x8*)(&Vimg[(bhb * 32 + kt) * 8192 + d * 64 + (((kk >> 3) ^ (d & 7)) << 3)]) = v;
    }
  }
}

// ---------------------------------------------------------------------------
// Kernel 4: flash attention, QBLK=128 DUAL-ACCUMULATOR: 4 waves x 32 q-rows
// (two 16-row sets A/B per wave). Every kf/vf LDS fragment read now feeds
// TWO MFMAs, and each staged KV tile serves 128 q-rows — halves the measured
// LDS bottleneck (R12/R17: ~2100 of 2970 cy/unit) per tile-unit.
// Grid 512 = 16 qt x 32 bh; qt(g) = g<8 ? g : 23-g so round-robin co-resident
// pairs (blocks c, c+256: same bh!) sum to exactly 34 tile-units.
// Reg-staged pipeline, exp2 softmax, T13 defer-max. Ps buffer reused
// sequentially by sets A/B (same-wave LDS ordering). LDS 40960 B;
// VGPR ~200 -> __launch_bounds__(256,2).
// ---------------------------------------------------------------------------
__global__ __launch_bounds__(256, 2)
void flash_kernel(const u16* __restrict__ Qb, const u16* __restrict__ Kimg,
                  const u16* __restrict__ Vimg, const u32* __restrict__ mbits,
                  u16* __restrict__ Ob)
{
  __shared__ __align__(16) u16 Ks[64 * 128];
  __shared__ __align__(16) u16 VTs[128 * 64];
  __shared__ __align__(16) u16 Ps[4][16 * 64];
  const int tid = threadIdx.x;
  const int g = blockIdx.x >> 5;
  const int qt = (g < 8) ? g : (23 - g);       // pair {g, 15-g} per CU
  const int bh = blockIdx.x & 31;
  const int q0 = qt * 128;
  const int wave = tid >> 6, lane = tid & 63;
  const int lr = lane & 15, lg = lane >> 4;
  const long base = (long)bh * T_ * 128;       // Q/O rows
  const long iblk = (long)bh * 32;             // image block index base
  const int ldsoff = wave * 2048 + lane * 8;   // staging offset (u16)
  const int qrlA = wave * 32 + lr;             // set A local q-row (0..127)
  const int qrlB = qrlA + 16;                  // set B
  const int swz = (lr & 7) << 1;               // Ps chunk swizzle (bit0-preserving)
  const int nkt = 2 * qt + 2;                  // KV tiles (64-wide) this q-block needs

  bf16x8 qfA[4], qfB[4];                       // Q rows as B-operands
  {
    const u16* qa = Qb + base + (long)(q0 + qrlA) * 128;
    const u16* qb = Qb + base + (long)(q0 + qrlB) * 128;
#pragma unroll
    for (int ks = 0; ks < 4; ++ks) {
      qfA[ks] = *(const bf16x8*)(&qa[lg * 8 + ks * 32]);
      qfB[ks] = *(const bf16x8*)(&qb[lg * 8 + ks * 32]);
    }
  }
  f32x4 accA[8], accB[8];                      // O^T: row=d, col=qrow=lr
#pragma unroll
  for (int i = 0; i < 8; ++i) {
    accA[i] = (f32x4){0.f, 0.f, 0.f, 0.f};
    accB[i] = (f32x4){0.f, 0.f, 0.f, 0.f};
  }
  float mrunA = -__builtin_inff(), lrunA = 0.f;
  float mrunB = -__builtin_inff(), lrunB = 0.f;

  // prefetch tile 0 into registers
  u16x8 kreg[4], vreg[4];
  {
    const u16* ks0 = Kimg + iblk * 8192 + ldsoff;
    const u16* vs0 = Vimg + iblk * 8192 + ldsoff;
#pragma unroll
    for (int i = 0; i < 4; ++i) {
      kreg[i] = *(const u16x8*)(ks0 + i * 512);
      vreg[i] = *(const u16x8*)(vs0 + i * 512);
    }
  }

  for (int kt = 0; kt < nkt; ++kt) {
    __syncthreads();                       // A: prev-tile readers done
#pragma unroll
    for (int i = 0; i < 4; ++i) {          // regs -> LDS (linear image layout)
      *(u16x8*)(&Ks[ldsoff + i * 512]) = kreg[i];
      *(u16x8*)(&VTs[ldsoff + i * 512]) = vreg[i];
    }
    __syncthreads();                       // B: drains ds_writes
    if (kt + 1 < nkt) {                    // prefetch next tile under compute
      const u16* ksn = Kimg + (iblk + kt + 1) * 8192 + ldsoff;
      const u16* vsn = Vimg + (iblk + kt + 1) * 8192 + ldsoff;
#pragma unroll
      for (int i = 0; i < 4; ++i) {
        kreg[i] = *(const u16x8*)(ksn + i * 512);
        vreg[i] = *(const u16x8*)(vsn + i * 512);
      }
    }
    // mask words for both q-rows
    u32 mwA0, mwA1, mwB0, mwB1;
    {
      const u32* mpA = &mbits[(q0 + qrlA) * 64 + kt * 2];
      const u32* mpB = &mbits[(q0 + qrlB) * 64 + kt * 2];
      mwA0 = mpA[0]; mwA1 = mpA[1];
      mwB0 = mpB[0]; mwB1 = mpB[1];
    }

    // S^T = K Q^T, both sets share each kf read
    f32x4 sA[4], sB[4];
    __builtin_amdgcn_s_setprio(1);
#pragma unroll
    for (int ft = 0; ft < 4; ++ft) {
      f32x4 a = (f32x4){0.f, 0.f, 0.f, 0.f};
      f32x4 b = (f32x4){0.f, 0.f, 0.f, 0.f};
#pragma unroll
      for (int ks = 0; ks < 4; ++ks) {
        int kr = ft * 16 + lr, chunk = lg + ks * 4;
        bf16x8 kf = *(const bf16x8*)(&Ks[kr * 128 + ((chunk ^ (kr & 15)) << 3)]);
        a = __builtin_amdgcn_mfma_f32_16x16x32_bf16(kf, qfA[ks], a, 0, 0, 0);
        b = __builtin_amdgcn_mfma_f32_16x16x32_bf16(kf, qfB[ks], b, 0, 0, 0);
      }
      sA[ft] = a; sB[ft] = b;
    }
    __builtin_amdgcn_s_setprio(0);
    // masking (key = ft*16 + lg*4 + r); causal only on last two tiles
    const bool diag = (kt >= 2 * qt);
    const int kv0 = kt * 64;
#pragma unroll
    for (int ft = 0; ft < 4; ++ft) {
      u32 wA = (ft & 2) ? mwA1 : mwA0;
      u32 wB = (ft & 2) ? mwB1 : mwB0;
      int kbase = ft * 16 + lg * 4;
      int sh = ((ft & 1) << 4) + lg * 4;
#pragma unroll
      for (int r = 0; r < 4; ++r) {
        bool visA = (wA >> (sh + r)) & 1u;
        bool visB = (wB >> (sh + r)) & 1u;
        if (diag) {
          int key = kv0 + kbase + r;
          if (key > q0 + qrlA) visA = false;
          if (key > q0 + qrlB) visB = false;
        }
        if (!visA) sA[ft][r] = -__builtin_inff();
        if (!visB) sB[ft][r] = -__builtin_inff();
      }
    }
    // ---- softmax set A (exp2 domain, T13 defer-max THR=8) ----
    {
      float t0 = fmaxf(fmaxf(sA[0][0], sA[0][1]), fmaxf(sA[0][2], sA[0][3]));
      float t1 = fmaxf(fmaxf(sA[1][0], sA[1][1]), fmaxf(sA[1][2], sA[1][3]));
      float t2 = fmaxf(fmaxf(sA[2][0], sA[2][1]), fmaxf(sA[2][2], sA[2][3]));
      float t3 = fmaxf(fmaxf(sA[3][0], sA[3][1]), fmaxf(sA[3][2], sA[3][3]));
      float tm = fmaxf(fmaxf(t0, t1), fmaxf(t2, t3));
      tm = fmaxf(tm, __shfl_xor(tm, 16));
      tm = fmaxf(tm, __shfl_xor(tm, 32));
      const bool skip = __all(tm - mrunA <= 8.0f);
      float fac = 1.0f;
      float msafe = (mrunA == -__builtin_inff()) ? 0.f : mrunA;
      if (!skip) {
        float mnew = fmaxf(mrunA, tm);
        msafe = (mnew == -__builtin_inff()) ? 0.f : mnew;
        fac = __builtin_amdgcn_exp2f(mrunA - msafe);
        mrunA = mnew;
      }
      float rs = 0.f;
#pragma unroll
      for (int ft = 0; ft < 4; ++ft) {
        float p0 = __builtin_amdgcn_exp2f(sA[ft][0] - msafe);
        float p1 = __builtin_amdgcn_exp2f(sA[ft][1] - msafe);
        float p2 = __builtin_amdgcn_exp2f(sA[ft][2] - msafe);
        float p3 = __builtin_amdgcn_exp2f(sA[ft][3] - msafe);
        sA[ft][0] = p0; sA[ft][1] = p1; sA[ft][2] = p2; sA[ft][3] = p3;
        rs += (p0 + p1) + (p2 + p3);
      }
      rs += __shfl_xor(rs, 16);
      rs += __shfl_xor(rs, 32);
      lrunA = lrunA * fac + rs;
      if (!skip) {
#pragma unroll
        for (int nt = 0; nt < 8; ++nt)
#pragma unroll
          for (int r = 0; r < 4; ++r) accA[nt][r] *= fac;
      }
    }
    // ---- softmax set B ----
    {
      float t0 = fmaxf(fmaxf(sB[0][0], sB[0][1]), fmaxf(sB[0][2], sB[0][3]));
      float t1 = fmaxf(fmaxf(sB[1][0], sB[1][1]), fmaxf(sB[1][2], sB[1][3]));
      float t2 = fmaxf(fmaxf(sB[2][0], sB[2][1]), fmaxf(sB[2][2], sB[2][3]));
      float t3 = fmaxf(fmaxf(sB[3][0], sB[3][1]), fmaxf(sB[3][2], sB[3][3]));
      float tm = fmaxf(fmaxf(t0, t1), fmaxf(t2, t3));
      tm = fmaxf(tm, __shfl_xor(tm, 16));
      tm = fmaxf(tm, __shfl_xor(tm, 32));
      const bool skip = __all(tm - mrunB <= 8.0f);
      float fac = 1.0f;
      float msafe = (mrunB == -__builtin_inff()) ? 0.f : mrunB;
      if (!skip) {
        float mnew = fmaxf(mrunB, tm);
        msafe = (mnew == -__builtin_inff()) ? 0.f : mnew;
        fac = __builtin_amdgcn_exp2f(mrunB - msafe);
        mrunB = mnew;
      }
      float rs = 0.f;
#pragma unroll
      for (int ft = 0; ft < 4; ++ft) {
        float p0 = __builtin_amdgcn_exp2f(sB[ft][0] - msafe);
        float p1 = __builtin_amdgcn_exp2f(sB[ft][1] - msafe);
        float p2 = __builtin_amdgcn_exp2f(sB[ft][2] - msafe);
        float p3 = __builtin_amdgcn_exp2f(sB[ft][3] - msafe);
        sB[ft][0] = p0; sB[ft][1] = p1; sB[ft][2] = p2; sB[ft][3] = p3;
        rs += (p0 + p1) + (p2 + p3);
      }
      rs += __shfl_xor(rs, 16);
      rs += __shfl_xor(rs, 32);
      lrunB = lrunB * fac + rs;
      if (!skip) {
#pragma unroll
        for (int nt = 0; nt < 8; ++nt)
#pragma unroll
          for (int r = 0; r < 4; ++r) accB[nt][r] *= fac;
      }
    }
    // P-pack set A -> Ps -> paA (same-wave LDS ordering), then set B
    bf16x8 paA[2], paB[2];
#pragma unroll
    for (int ft = 0; ft < 4; ++ft) {
      u16 h0 = f2bf(sA[ft][0]), h1 = f2bf(sA[ft][1]);
      u16 h2 = f2bf(sA[ft][2]), h3 = f2bf(sA[ft][3]);
      u32x2 pw; pw[0] = (u32)h0 | ((u32)h1 << 16); pw[1] = (u32)h2 | ((u32)h3 << 16);
      int ch4 = (ft * 4 + lg) ^ swz;
      *(u32x2*)(&Ps[wave][lr * 64 + ch4 * 4]) = pw;
    }
#pragma unroll
    for (int s2 = 0; s2 < 2; ++s2) {
      int ch4b = (s2 * 8 + lg * 2) ^ swz;
      paA[s2] = *(const bf16x8*)(&Ps[wave][lr * 64 + ch4b * 4]);
    }
#pragma unroll
    for (int ft = 0; ft < 4; ++ft) {
      u16 h0 = f2bf(sB[ft][0]), h1 = f2bf(sB[ft][1]);
      u16 h2 = f2bf(sB[ft][2]), h3 = f2bf(sB[ft][3]);
      u32x2 pw; pw[0] = (u32)h0 | ((u32)h1 << 16); pw[1] = (u32)h2 | ((u32)h3 << 16);
      int ch4 = (ft * 4 + lg) ^ swz;
      *(u32x2*)(&Ps[wave][lr * 64 + ch4 * 4]) = pw;
    }
#pragma unroll
    for (int s2 = 0; s2 < 2; ++s2) {
      int ch4b = (s2 * 8 + lg * 2) ^ swz;
      paB[s2] = *(const bf16x8*)(&Ps[wave][lr * 64 + ch4b * 4]);
    }
    // O^T += V^T P, both sets share each vf read
    __builtin_amdgcn_s_setprio(1);
#pragma unroll
    for (int nt = 0; nt < 8; ++nt)
#pragma unroll
      for (int s2 = 0; s2 < 2; ++s2) {
        int d = nt * 16 + lr, chunk = lg + s2 * 4;
        bf16x8 vf = *(const bf16x8*)(&VTs[d * 64 + ((chunk ^ (d & 7)) << 3)]);
        accA[nt] = __builtin_amdgcn_mfma_f32_16x16x32_bf16(vf, paA[s2], accA[nt], 0, 0, 0);
        accB[nt] = __builtin_amdgcn_mfma_f32_16x16x32_bf16(vf, paB[s2], accB[nt], 0, 0, 0);
      }
    __builtin_amdgcn_s_setprio(0);
  }
  const float invA = (lrunA > 0.f) ? 1.f / lrunA : 0.f;
  const float invB = (lrunB > 0.f) ? 1.f / lrunB : 0.f;
  const long orowA = base + (long)(q0 + qrlA) * 128;
  const long orowB = base + (long)(q0 + qrlB) * 128;
#pragma unroll
  for (int nt = 0; nt < 8; ++nt) {
    u16 a0 = f2bf(accA[nt][0] * invA), a1 = f2bf(accA[nt][1] * invA);
    u16 a2 = f2bf(accA[nt][2] * invA), a3 = f2bf(accA[nt][3] * invA);
    u32x2 owA; owA[0] = (u32)a0 | ((u32)a1 << 16); owA[1] = (u32)a2 | ((u32)a3 << 16);
    *(u32x2*)(&Ob[orowA + nt * 16 + lg * 4]) = owA;
    u16 b0 = f2bf(accB[nt][0] * invB), b1 = f2bf(accB[nt][1] * invB);
    u16 b2 = f2bf(accB[nt][2] * invB), b3 = f2bf(accB[nt][3] * invB);
    u32x2 owB; owB[0] = (u32)b0 | ((u32)b1 << 16); owB[1] = (u32)b2 | ((u32)b3 << 16);
    *(u32x2*)(&Ob[orowB + nt * 16 + lg * 4]) = owB;
  }
}

// ---------------------------------------------------------------------------
// Kernel 5a: degenerate-row partial sums. Block = (ksec, bh, slot):
// sums V[bh, ksec*64 .. +63, d] over mask==0 -> partial[slot][bh][d][ksec].
// partial aliases Qb (dead after flash). No memset/atomics needed.
// ---------------------------------------------------------------------------
__global__ __launch_bounds__(256)
void fixup_partial_kernel(const u32* __restrict__ deglist, const u32* __restrict__ degcount,
                          const u32* __restrict__ mbits, const u16* __restrict__ Vimg,
                          float* __restrict__ partial)
{
  const int slot = blockIdx.z;
  const u32 cnt = *degcount;
  if (slot >= (int)cnt) return;
  const int ksec = blockIdx.x, bh = blockIdx.y;
  const int q = (int)deglist[slot];
  const int t = threadIdx.x;
  const int d = t & 127, kc = t >> 7;          // kc in {0,1}: chunks 0-3 / 4-7
  const u16* vb = Vimg + ((long)bh * 32 + ksec) * 8192 + d * 64;
  const u32 w0 = mbits[q * 64 + ksec * 2];
  const u32 w1 = mbits[q * 64 + ksec * 2 + 1];
  float a = 0.f;
#pragma unroll
  for (int i = 0; i < 4; ++i) {
    int c = kc * 4 + i;                        // chunk 0..7, covers k = ksec*64 + c*8 ..+7
    u32 bits = ((kc == 0) ? (w0 >> (c * 8)) : (w1 >> ((c - 4) * 8))) & 0xffu;
    u16x8 v = *(const u16x8*)(&vb[(c ^ (d & 7)) << 3]);
#pragma unroll
    for (int j = 0; j < 8; ++j)
      a += ((bits >> j) & 1u) ? 0.f : bf2f(v[j]);
  }
  __shared__ float tmp[2][128];
  tmp[kc][d] = a;
  __syncthreads();
  if (t < 128)
    partial[(((long)slot * BH_ + bh) * 128 + d) * 32 + ksec] = tmp[0][d] + tmp[1][d];
}

// ---------------------------------------------------------------------------
// Kernel 5b: combine partials -> Ob. Grid (8 slots, 32 bh), 128 threads.
// ---------------------------------------------------------------------------
__global__ __launch_bounds__(128)
void fixup_combine_kernel(const u32* __restrict__ deglist, const u32* __restrict__ degcount,
                          const float* __restrict__ cnt0inv, const float* __restrict__ partial,
                          u16* __restrict__ Ob)
{
  const int slot = blockIdx.x;
  const u32 cnt = *degcount;
  if (slot >= (int)cnt) return;
  const int bh = blockIdx.y;
  const int q = (int)deglist[slot];
  const int d = threadIdx.x;
  const float* p = partial + (((long)slot * BH_ + bh) * 128 + d) * 32;
  float s = 0.f;
#pragma unroll
  for (int i = 0; i < 8; ++i) {
    f32x4 v = *(const f32x4*)(&p[i * 4]);
    s += (v[0] + v[1]) + (v[2] + v[3]);
  }
  Ob[((long)bh * T_ + q) * 128 + d] = f2bf(s * cnt0inv[q]);
}

// ---------------------------------------------------------------------------
// Kernel 5c: fallback for slots >= 8 (pathological masks; never runs for the
// bench mask — all blocks exit after two loads). Same math, serial per row.
// ---------------------------------------------------------------------------
__global__ __launch_bounds__(256)
void fixup_slow_kernel(const u32* __restrict__ deglist, const u32* __restrict__ degcount,
                       const float* __restrict__ cnt0inv, const u32* __restrict__ mbits,
                       const u16* __restrict__ Vimg, u16* __restrict__ Ob)
{
  const u32 cnt = *degcount;
  const int bh = blockIdx.y;
  const int d = threadIdx.x & 127, half = threadIdx.x >> 7;
  __shared__ float tmp[2][128];
  const u16* vb = Vimg + (long)bh * 32 * 8192;
  for (u32 idx = 8 + blockIdx.x; idx < cnt; idx += gridDim.x) {
    const int q = (int)deglist[idx];
    const float inv = cnt0inv[q];
    float a = 0.f;
#pragma unroll 16
    for (int i = 0; i < 128; ++i) {
      int k0 = half * 1024 + i * 8;
      u32 w = mbits[q * 64 + (k0 >> 5)];
      u32 bits = (w >> (k0 & 31)) & 0xffu;
      int kt = k0 >> 6, kk = k0 & 63;
      u16x8 v = *(const u16x8*)(&vb[(long)kt * 8192 + d * 64 + (((kk >> 3) ^ (d & 7)) << 3)]);
#pragma unroll
      for (int j = 0; j < 8; ++j)
        a += ((bits >> j) & 1u) ? 0.f : bf2f(v[j]);
    }
    tmp[half][d] = a;
    __syncthreads();
    if (half == 0)
      Ob[((long)bh * T_ + q) * 128 + d] = f2bf((tmp[0][d] + tmp[1][d]) * inv);
    __syncthreads();
  }
}

// ---------------------------------------------------------------------------
// Kernel 6: output projection. out[8192 x 128] = A[8192 x 1024] * Wu + bu,
// A[m][h*128+d] = O[(b,h,t,d)]. 32-row tiles, K chunk = one head (128).
// ---------------------------------------------------------------------------
__global__ __launch_bounds__(256)
void outproj_kernel(const u16* __restrict__ Ob, const u16* __restrict__ WuT,
                    const float* __restrict__ bu, float* __restrict__ out)
{
  __shared__ __align__(16) u16 As[32 * 128];
  __shared__ __align__(16) u16 Bs[128 * 128];
  const int tid = threadIdx.x;
  const int m0 = blockIdx.x * 32;
  const int wave = tid >> 6, lane = tid & 63;
  const int lr = lane & 15, lg = lane >> 4;
  f32x4 acc[2][2];
#pragma unroll
  for (int a = 0; a < 2; ++a)
#pragma unroll
    for (int b = 0; b < 2; ++b) acc[a][b] = (f32x4){0.f, 0.f, 0.f, 0.f};
  for (int kc = 0; kc < 8; ++kc) {
    __syncthreads();
#pragma unroll
    for (int i = 0; i < 2; ++i) {
      int c = tid + 256 * i;               // 512 chunks
      int row = c >> 4, d0 = (c & 15) * 8;
      int m = m0 + row, bb = m >> 11, t = m & 2047;
      *(u16x8*)(&As[row * 128 + ((((d0 >> 3)) ^ (row & 15)) << 3)]) =
          *(const u16x8*)(&Ob[((long)(bb * H_ + kc) * T_ + t) * 128 + d0]);
    }
#pragma unroll
    for (int i = 0; i < 8; ++i) {
      int c = tid + 256 * i;               // 2048 chunks
      int row = c >> 4, d0 = (c & 15) * 8;
      *(u16x8*)(&Bs[row * 128 + ((((d0 >> 3)) ^ (row & 15)) << 3)]) =
          *(const u16x8*)(&WuT[row * 1024 + kc * 128 + d0]);
    }
    __syncthreads();
#pragma unroll
    for (int ks = 0; ks < 4; ++ks) {
      bf16x8 af[2], bf2[2];
#pragma unroll
      for (int mt = 0; mt < 2; ++mt) {
        int row = mt * 16 + lr, chunk = lg + ks * 4;
        af[mt] = *(const bf16x8*)(&As[row * 128 + ((chunk ^ (row & 15)) << 3)]);
      }
#pragma unroll
      for (int nt = 0; nt < 2; ++nt) {
        int row = wave * 32 + nt * 16 + lr, chunk = lg + ks * 4;
        bf2[nt] = *(const bf16x8*)(&Bs[row * 128 + ((chunk ^ (row & 15)) << 3)]);
      }
#pragma unroll
      for (int mt = 0; mt < 2; ++mt)
#pragma unroll
        for (int nt = 0; nt < 2; ++nt)
          acc[mt][nt] = __builtin_amdgcn_mfma_f32_16x16x32_bf16(af[mt], bf2[nt], acc[mt][nt], 0, 0, 0);
    }
  }
#pragma unroll
  for (int mt = 0; mt < 2; ++mt)
#pragma unroll
    for (int nt = 0; nt < 2; ++nt) {
      int n = wave * 32 + nt * 16 + lr;
      float bias = bu[n];
#pragma unroll
      for (int r = 0; r < 4; ++r) {
        int m = m0 + mt * 16 + lg * 4 + r;
        out[(long)m * 128 + n] = acc[mt][nt][r] + bias;
      }
    }
}

// ---------------------------------------------------------------------------
extern "C" void kernel_launch(void* const* d_in, const int* in_sizes, int n_in,
                              void* d_out, int out_size, void* d_ws, size_t ws_size,
                              hipStream_t stream)
{
  (void)in_sizes; (void)n_in; (void)out_size; (void)ws_size;
  const float* x   = (const float*)d_in[0];
  const int*   msk = (const int*)d_in[1];
  const float* Wq  = (const float*)d_in[2];
  const float* Wk  = (const float*)d_in[3];
  const float* Wv  = (const float*)d_in[4];
  const float* Wu  = (const float*)d_in[5];
  const float* bu  = (const float*)d_in[6];
  float* out = (float*)d_out;

  // workspace layout (bf16 elements unless noted); total ~67.6 MB
  u16* Qb   = (u16*)d_ws;
  u16* Kimg = Qb + (size_t)BH_ * T_ * 128;      // [bh][32][8192] swizzled image
  u16* Vimg = Kimg + (size_t)BH_ * T_ * 128;    // [bh][32][8192] swizzled image
  u16* Obf  = Vimg + (size_t)BH_ * T_ * 128;
  u16* xb   = Obf + (size_t)BH_ * T_ * 128;
  u16* WT   = xb + (size_t)M_ * 128;            // [3072][128]
  u16* WuT  = WT + (size_t)3072 * 128;          // [128][1024]
  u32* mbits   = (u32*)(WuT + (size_t)128 * 1024);
  u32* deglist = mbits + (size_t)2048 * 64;
  u32* degcount = deglist + 2048;
  float* cnt0inv = (float*)(degcount + 1);
  // fixup partials alias Qb: dead after flash_kernel; 8*32*128*32*4 B = 4 MB
  float* partial = (float*)Qb;

  hipMemsetAsync(degcount, 0, sizeof(u32), stream);
  prep_kernel<<<6144, 256, 0, stream>>>(x, Wq, Wk, Wv, Wu, xb, WT, WuT);
  maskprep_kernel<<<512, 256, 0, stream>>>(msk, mbits, deglist, degcount, cnt0inv);
  qkv_kernel<<<dim3(24, 64), 256, 0, stream>>>(xb, WT, Qb, Kimg, Vimg);
  flash_kernel<<<512, 256, 0, stream>>>(Qb, Kimg, Vimg, mbits, Obf);
  fixup_partial_kernel<<<dim3(32, 32, 8), 256, 0, stream>>>(deglist, degcount, mbits, Vimg, partial);
  fixup_combine_kernel<<<dim3(8, 32), 128, 0, stream>>>(deglist, degcount, cnt0inv, partial, Obf);
  fixup_slow_kernel<<<dim3(32, 32), 256, 0, stream>>>(deglist, degcount, cnt0inv, mbits, Vimg, Obf);
  outproj_kernel<<<256, 256, 0, stream>>>(Obf, WuT, bu, out);
}

// Round 19
// 154.929 us; speedup vs baseline: 1.0347x; 1.0347x over previous
//
#include <hip/hip_runtime.h>
#include <hip/hip_bf16.h>

typedef unsigned short u16;
typedef unsigned int u32;
typedef __attribute__((ext_vector_type(8))) short bf16x8;   // 8 bf16 = 4 VGPR (MFMA A/B frag)
typedef __attribute__((ext_vector_type(4))) float f32x4;    // MFMA C/D frag
typedef __attribute__((ext_vector_type(8))) unsigned short u16x8;
typedef __attribute__((ext_vector_type(2))) unsigned int u32x2;

#define T_ 2048
#define H_ 8
#define BH_ 32
#define M_ 8192
#define SCALE_QK 0.29730177875068026f   // 128^(-0.25), folded into Wq and Wk
#define LOG2E 1.4426950408889634f       // extra factor on Wq -> softmax in exp2 domain

__device__ __forceinline__ u16 f2bf(float f) {
  union { __hip_bfloat16 h; u16 u; } cv; cv.h = __float2bfloat16(f); return cv.u;
}
__device__ __forceinline__ float bf2f(u16 u) {
  union { u16 u; __hip_bfloat16 h; } cv; cv.u = u; return __bfloat162float(cv.h);
}

// K image block (bh,kt): 64x128 tile, elem(kr,d) at kr*128 + (((d>>3)^(kr&15))<<3) + (d&7)
// V image block (bh,kt): 128x64 tile, elem(d,kk) at d*64  + (((kk>>3)^(d&7))<<3)  + (kk&7)
// Both are verbatim images of the flash kernel's swizzled LDS tiles.
// (R16 lesson: V MUST be LDS-staged — direct per-fragment global reads
// overfetch HBM 8.7x; LDS staging is the coalescing mechanism.)

// ---------------------------------------------------------------------------
// Kernel 1: prep — x -> bf16; Wq/Wk/Wv -> WT[n][k] bf16 (scale folded for q,k;
// Wq additionally scaled by log2e so flash softmax runs in exp2 domain);
// Wu -> WuT[n][k] bf16.
// ---------------------------------------------------------------------------
__global__ __launch_bounds__(256)
void prep_kernel(const float* __restrict__ x, const float* __restrict__ Wq,
                 const float* __restrict__ Wk, const float* __restrict__ Wv,
                 const float* __restrict__ Wu,
                 u16* __restrict__ xb, u16* __restrict__ WT, u16* __restrict__ WuT)
{
  int i = blockIdx.x * 256 + threadIdx.x;
  if (i < M_ * 128) { xb[i] = f2bf(x[i]); return; }
  int j = i - M_ * 128;
  if (j < 3072 * 128) {
    int n = j >> 7, k = j & 127;
    float w;
    if (n < 1024)      w = Wq[k * 1024 + n] * (SCALE_QK * LOG2E);
    else if (n < 2048) w = Wk[k * 1024 + (n - 1024)] * SCALE_QK;
    else               w = Wv[k * 1024 + (n - 2048)];
    WT[j] = f2bf(w);
    return;
  }
  int u = j - 3072 * 128;
  if (u < 128 * 1024) {
    int n = u >> 10, k = u & 1023;
    WuT[u] = f2bf(Wu[k * 128 + n]);
  }
}

// ---------------------------------------------------------------------------
// Kernel 2: maskprep — pack mask row q into 64 u32 bitwords (bit=mask!=0);
// degenerate rows -> deglist (atomic append); cnt0inv[q]. One wave per row.
// ---------------------------------------------------------------------------
__global__ __launch_bounds__(256)
void maskprep_kernel(const int* __restrict__ mask, u32* __restrict__ mbits,
                     u32* __restrict__ deglist, u32* __restrict__ degcount,
                     float* __restrict__ cnt0inv)
{
  int wave = threadIdx.x >> 6, lane = threadIdx.x & 63;
  int q = blockIdx.x * 4 + wave;
  const int* row = mask + (long)q * 2048;
  unsigned long long anyvis = 0ull;
  int cnt1 = 0;
  for (int it = 0; it < 32; ++it) {
    int k = it * 64 + lane;
    unsigned long long bal = __ballot(row[k] != 0);
    if (lane == 0) {
      mbits[q * 64 + it * 2]     = (u32)bal;
      mbits[q * 64 + it * 2 + 1] = (u32)(bal >> 32);
    }
    cnt1 += __popcll(bal);
    int lim = q - it * 64;                      // visible lane offsets: 0..lim
    if (lim >= 63)      anyvis |= bal;
    else if (lim >= 0)  anyvis |= (bal & ((2ull << lim) - 1ull));
  }
  if (lane == 0) {
    int c0 = 2048 - cnt1;
    cnt0inv[q] = (c0 > 0) ? 1.0f / (float)c0 : 0.0f;
    if (anyvis == 0ull) {
      u32 slot = atomicAdd(degcount, 1u);
      deglist[slot] = (u32)q;
    }
  }
}

// ---------------------------------------------------------------------------
// Kernel 3: QKV projection GEMM. 128x128 tile, K=128, 4 waves, 16x16x32 MFMA.
// All epilogues go through LDS staging -> coalesced u16x8 global stores
// (no scalar global scatter). Q row-major; K,V as swizzled image blocks.
// ---------------------------------------------------------------------------
__global__ __launch_bounds__(256)
void qkv_kernel(const u16* __restrict__ xb, const u16* __restrict__ WT,
                u16* __restrict__ Qb, u16* __restrict__ Kimg, u16* __restrict__ Vimg)
{
  __shared__ __align__(16) u16 As[128 * 128];
  __shared__ __align__(16) u16 Bs[128 * 128];
  const int tid = threadIdx.x;
  const int n0 = blockIdx.x * 128;    // over concat [Wq|Wk|Wv] = 3072 cols
  const int m0 = blockIdx.y * 128;
#pragma unroll
  for (int i = 0; i < 8; ++i) {
    int c = tid + 256 * i;            // 2048 chunks of 8 elems
    int row = c >> 4, d0 = (c & 15) * 8;
    int soff = row * 128 + ((((d0 >> 3)) ^ (row & 15)) << 3);
    *(u16x8*)(&As[soff]) = *(const u16x8*)(&xb[(m0 + row) * 128 + d0]);
    *(u16x8*)(&Bs[soff]) = *(const u16x8*)(&WT[(n0 + row) * 128 + d0]);
  }
  __syncthreads();
  const int wave = tid >> 6, lane = tid & 63;
  const int lr = lane & 15, lg = lane >> 4;
  const int wm = (wave >> 1) * 64, wn = (wave & 1) * 64;
  f32x4 acc[4][4];
#pragma unroll
  for (int a = 0; a < 4; ++a)
#pragma unroll
    for (int b = 0; b < 4; ++b) acc[a][b] = (f32x4){0.f, 0.f, 0.f, 0.f};
#pragma unroll
  for (int ks = 0; ks < 4; ++ks) {
    bf16x8 af[4], bf[4];
#pragma unroll
    for (int mt = 0; mt < 4; ++mt) {
      int row = wm + mt * 16 + lr, chunk = lg + ks * 4;
      af[mt] = *(const bf16x8*)(&As[row * 128 + ((chunk ^ (row & 15)) << 3)]);
    }
#pragma unroll
    for (int nt = 0; nt < 4; ++nt) {
      int row = wn + nt * 16 + lr, chunk = lg + ks * 4;
      bf[nt] = *(const bf16x8*)(&Bs[row * 128 + ((chunk ^ (row & 15)) << 3)]);
    }
#pragma unroll
    for (int mt = 0; mt < 4; ++mt)
#pragma unroll
      for (int nt = 0; nt < 4; ++nt)
        acc[mt][nt] = __builtin_amdgcn_mfma_f32_16x16x32_bf16(af[mt], bf[nt], acc[mt][nt], 0, 0, 0);
  }
  const int mat = n0 >> 10;
  const int hh = (n0 & 1023) >> 7;
  const int bb = m0 >> 11;
  const long bhb = (long)(bb * H_ + hh);
  __syncthreads();                       // done reading As/Bs; reuse As
  if (mat != 2) {
    // stage C tile [tl][d] (chunk-swizzled), then vectorized stores
#pragma unroll
    for (int mt = 0; mt < 4; ++mt)
#pragma unroll
      for (int nt = 0; nt < 4; ++nt)
#pragma unroll
        for (int r = 0; r < 4; ++r) {
          int tl = wm + mt * 16 + lg * 4 + r;
          int d  = wn + nt * 16 + lr;
          As[tl * 128 + ((((d >> 3)) ^ (tl & 15)) << 3) + (d & 7)] = f2bf(acc[mt][nt][r]);
        }
    __syncthreads();
    if (mat == 0) {
#pragma unroll
      for (int i = 0; i < 8; ++i) {
        int c = tid + 256 * i;
        int row = c >> 4, d0 = (c & 15) * 8;
        u16x8 v = *(const u16x8*)(&As[row * 128 + ((((d0 >> 3)) ^ (row & 15)) << 3)]);
        *(u16x8*)(&Qb[(bhb * T_ + ((m0 + row) & 2047)) * 128 + d0]) = v;
      }
    } else {
#pragma unroll
      for (int i = 0; i < 8; ++i) {
        int c = tid + 256 * i;
        int row = c >> 4, d0 = (c & 15) * 8;
        u16x8 v = *(const u16x8*)(&As[row * 128 + ((((d0 >> 3)) ^ (row & 15)) << 3)]);
        int t = (m0 + row) & 2047;
        int kt = t >> 6, kr = t & 63;
        *(u16x8*)(&Kimg[(bhb * 32 + kt) * 8192 + kr * 128 + ((((d0 >> 3)) ^ (kr & 15)) << 3)]) = v;
      }
    }
  } else {
    // transpose V tile in LDS (reuse As), then u16x8 stores into V image blocks
    u16* TT = As;
#pragma unroll
    for (int mt = 0; mt < 4; ++mt)
#pragma unroll
      for (int nt = 0; nt < 4; ++nt)
#pragma unroll
        for (int r = 0; r < 4; ++r) {
          int tl = wm + mt * 16 + lg * 4 + r;   // local t 0..127
          int d  = wn + nt * 16 + lr;
          TT[d * 128 + ((((tl >> 3)) ^ (d & 15)) << 3) + (tl & 7)] = f2bf(acc[mt][nt][r]);
        }
    __syncthreads();
    const int tg0 = m0 & 2047;
#pragma unroll
    for (int i = 0; i < 8; ++i) {
      int c = tid + 256 * i;
      int d = c >> 4, t0 = (c & 15) * 8;
      u16x8 v = *(const u16x8*)(&TT[d * 128 + ((((t0 >> 3)) ^ (d & 15)) << 3)]);
      int tg = tg0 + t0;
      int kt = tg >> 6, kk = tg & 63;
      *(u16x8*)(&Vimg[(bhb * 32 + kt) * 8192 + d * 64 + (((kk >> 3) ^ (d & 7)) << 3)]) = v;
    }
  }
}

// ---------------------------------------------------------------------------
// Kernel 4: flash attention (R17 structure) at FULL occupancy: measured VGPR
// is 84 (<=128) and LDS 40960*4 = 163840 B = exactly the CU's LDS capacity,
// so __launch_bounds__(256,4) admits a 4th resident block (R17 used (256,3)
// out of unfounded VGPR caution). The quad-balanced qt mapping was designed
// for 4 co-resident blocks (sums to 66 tile-units) — now grouped correctly.
// SWAPPED operands, 16x16x32 MFMA, reg-staged pipeline, exp2 softmax, T13.
// ---------------------------------------------------------------------------
__global__ __launch_bounds__(256, 4)
void flash_kernel(const u16* __restrict__ Qb, const u16* __restrict__ Kimg,
                  const u16* __restrict__ Vimg, const u32* __restrict__ mbits,
                  u16* __restrict__ Ob)
{
  __shared__ __align__(16) u16 Ks[64 * 128];
  __shared__ __align__(16) u16 VTs[128 * 64];
  __shared__ __align__(16) u16 Ps[4][16 * 64];
  const int tid = threadIdx.x;
  // quad-balanced qt permutation: g=b>>5, a=g&7, quad=g>>3
  const int g = blockIdx.x >> 5;
  const int a_ = g & 7, quad = g >> 3;
  const int qt = (quad == 0) ? (31 - a_) : (quad == 1) ? (8 + a_)
               : (quad == 2) ? (23 - a_) : a_;
  const int bh = blockIdx.x & 31;
  const int q0 = qt * 64;
  const int wave = tid >> 6, lane = tid & 63;
  const int lr = lane & 15, lg = lane >> 4;
  const long base = (long)bh * T_ * 128;       // Q/O rows
  const long iblk = (long)bh * 32;             // image block index base
  const int ldsoff = wave * 2048 + lane * 8;   // this thread's staging offset (u16)
  const int qrl = wave * 16 + lr;              // this lane's local q-row (0..63)
  const int swz = (lr & 7) << 1;               // Ps chunk swizzle (bit0-preserving)

  bf16x8 qf[4];                                // Q[q0+qrl][.] as B-operand
  {
    const u16* qrow = Qb + base + (long)(q0 + qrl) * 128;
#pragma unroll
    for (int ks = 0; ks < 4; ++ks)
      qf[ks] = *(const bf16x8*)(&qrow[lg * 8 + ks * 32]);
  }
  f32x4 acc[8];                                // O^T: row=d, col=qrow=lr
#pragma unroll
  for (int i = 0; i < 8; ++i) acc[i] = (f32x4){0.f, 0.f, 0.f, 0.f};
  float mrun = -__builtin_inff(), lrun = 0.f;

  // prefetch tile 0 into registers
  u16x8 kreg[4], vreg[4];
  {
    const u16* ks0 = Kimg + iblk * 8192 + ldsoff;
    const u16* vs0 = Vimg + iblk * 8192 + ldsoff;
#pragma unroll
    for (int i = 0; i < 4; ++i) {
      kreg[i] = *(const u16x8*)(ks0 + i * 512);
      vreg[i] = *(const u16x8*)(vs0 + i * 512);
    }
  }

  for (int kt = 0; kt <= qt; ++kt) {
    __syncthreads();                       // A: prev-tile readers done
#pragma unroll
    for (int i = 0; i < 4; ++i) {          // regs -> LDS (linear image layout)
      *(u16x8*)(&Ks[ldsoff + i * 512]) = kreg[i];
      *(u16x8*)(&VTs[ldsoff + i * 512]) = vreg[i];
    }
    __syncthreads();                       // B: drains ds_writes; vm queue empty
    // issue next tile's K/V loads — they complete during the compute below
    if (kt < qt) {
      const u16* ksn = Kimg + (iblk + kt + 1) * 8192 + ldsoff;
      const u16* vsn = Vimg + (iblk + kt + 1) * 8192 + ldsoff;
#pragma unroll
      for (int i = 0; i < 4; ++i) {
        kreg[i] = *(const u16x8*)(ksn + i * 512);
        vreg[i] = *(const u16x8*)(vsn + i * 512);
      }
    }
    // mask words for this lane's q-row (used after QK; latency hidden)
    u32 mw0, mw1;
    {
      const u32* mp = &mbits[(q0 + qrl) * 64 + kt * 2];
      mw0 = mp[0]; mw1 = mp[1];
    }

    // S^T = K Q^T : lane holds S[qrow=lr][key=ft*16+lg*4+r]
    f32x4 s[4];
    __builtin_amdgcn_s_setprio(1);
#pragma unroll
    for (int ft = 0; ft < 4; ++ft) {
      f32x4 sa = (f32x4){0.f, 0.f, 0.f, 0.f};
#pragma unroll
      for (int ks = 0; ks < 4; ++ks) {
        int kr = ft * 16 + lr, chunk = lg + ks * 4;
        bf16x8 kf = *(const bf16x8*)(&Ks[kr * 128 + ((chunk ^ (kr & 15)) << 3)]);
        sa = __builtin_amdgcn_mfma_f32_16x16x32_bf16(kf, qf[ks], sa, 0, 0, 0);
      }
      s[ft] = sa;
    }
    __builtin_amdgcn_s_setprio(0);
    // masking (key = ft*16 + lg*4 + r, all in-lane)
    const bool diag = (kt == qt);
#pragma unroll
    for (int ft = 0; ft < 4; ++ft) {
      u32 w = (ft & 2) ? mw1 : mw0;
      int kbase = ft * 16 + lg * 4;
      int sh = ((ft & 1) << 4) + lg * 4;
#pragma unroll
      for (int r = 0; r < 4; ++r) {
        bool vis = (w >> (sh + r)) & 1u;
        if (diag && (kbase + r) > qrl) vis = false;
        if (!vis) s[ft][r] = -__builtin_inff();
      }
    }
    // online softmax (exp2 domain) with defer-max (T13, THR=8)
    float t0 = fmaxf(fmaxf(s[0][0], s[0][1]), fmaxf(s[0][2], s[0][3]));
    float t1 = fmaxf(fmaxf(s[1][0], s[1][1]), fmaxf(s[1][2], s[1][3]));
    float t2 = fmaxf(fmaxf(s[2][0], s[2][1]), fmaxf(s[2][2], s[2][3]));
    float t3 = fmaxf(fmaxf(s[3][0], s[3][1]), fmaxf(s[3][2], s[3][3]));
    float tm = fmaxf(fmaxf(t0, t1), fmaxf(t2, t3));
    tm = fmaxf(tm, __shfl_xor(tm, 16));
    tm = fmaxf(tm, __shfl_xor(tm, 32));
    // skip if EVERY q-row's tile-max is within THR of its running max
    // (fresh rows: mrun=-inf -> tm-mrun=+inf/NaN -> no skip)
    const bool skip = __all(tm - mrun <= 8.0f);
    float fac = 1.0f;
    float msafe = (mrun == -__builtin_inff()) ? 0.f : mrun;
    if (!skip) {
      float mnew = fmaxf(mrun, tm);
      msafe = (mnew == -__builtin_inff()) ? 0.f : mnew;
      fac = __builtin_amdgcn_exp2f(mrun - msafe);
      mrun = mnew;
    }
    float rs = 0.f;
#pragma unroll
    for (int ft = 0; ft < 4; ++ft) {
      float p0 = __builtin_amdgcn_exp2f(s[ft][0] - msafe);
      float p1 = __builtin_amdgcn_exp2f(s[ft][1] - msafe);
      float p2 = __builtin_amdgcn_exp2f(s[ft][2] - msafe);
      float p3 = __builtin_amdgcn_exp2f(s[ft][3] - msafe);
      s[ft][0] = p0; s[ft][1] = p1; s[ft][2] = p2; s[ft][3] = p3;
      rs += (p0 + p1) + (p2 + p3);
    }
    rs += __shfl_xor(rs, 16);
    rs += __shfl_xor(rs, 32);
    lrun = lrun * fac + rs;
    if (!skip) {
#pragma unroll
      for (int nt = 0; nt < 8; ++nt)
#pragma unroll
        for (int r = 0; r < 4; ++r) acc[nt][r] *= fac;
    }
    // P-pack: 4 keys per ft are consecutive -> one b64 write each
#pragma unroll
    for (int ft = 0; ft < 4; ++ft) {
      u16 h0 = f2bf(s[ft][0]), h1 = f2bf(s[ft][1]);
      u16 h2 = f2bf(s[ft][2]), h3 = f2bf(s[ft][3]);
      u32x2 pw; pw[0] = (u32)h0 | ((u32)h1 << 16); pw[1] = (u32)h2 | ((u32)h3 << 16);
      int ch4 = (ft * 4 + lg) ^ swz;
      *(u32x2*)(&Ps[wave][lr * 64 + ch4 * 4]) = pw;
    }
    bf16x8 pa[2];                          // P[qrow=lr][k=s2*32+lg*8+j] (B-operand)
#pragma unroll
    for (int s2 = 0; s2 < 2; ++s2) {
      int ch4b = (s2 * 8 + lg * 2) ^ swz;
      pa[s2] = *(const bf16x8*)(&Ps[wave][lr * 64 + ch4b * 4]);
    }
    __builtin_amdgcn_s_setprio(1);
#pragma unroll
    for (int nt = 0; nt < 8; ++nt)
#pragma unroll
      for (int s2 = 0; s2 < 2; ++s2) {
        int d = nt * 16 + lr, chunk = lg + s2 * 4;
        bf16x8 vf = *(const bf16x8*)(&VTs[d * 64 + ((chunk ^ (d & 7)) << 3)]);
        acc[nt] = __builtin_amdgcn_mfma_f32_16x16x32_bf16(vf, pa[s2], acc[nt], 0, 0, 0);
      }
    __builtin_amdgcn_s_setprio(0);
  }
  const float inv = (lrun > 0.f) ? 1.f / lrun : 0.f;
  const long orow = base + (long)(q0 + qrl) * 128;
#pragma unroll
  for (int nt = 0; nt < 8; ++nt) {
    u16 h0 = f2bf(acc[nt][0] * inv), h1 = f2bf(acc[nt][1] * inv);
    u16 h2 = f2bf(acc[nt][2] * inv), h3 = f2bf(acc[nt][3] * inv);
    u32x2 ow; ow[0] = (u32)h0 | ((u32)h1 << 16); ow[1] = (u32)h2 | ((u32)h3 << 16);
    *(u32x2*)(&Ob[orow + nt * 16 + lg * 4]) = ow;
  }
}

// ---------------------------------------------------------------------------
// Kernel 5a: degenerate-row partial sums. Block = (ksec, bh, slot):
// sums V[bh, ksec*64 .. +63, d] over mask==0 -> partial[slot][bh][d][ksec].
// partial aliases Qb (dead after flash). No memset/atomics needed.
// ---------------------------------------------------------------------------
__global__ __launch_bounds__(256)
void fixup_partial_kernel(const u32* __restrict__ deglist, const u32* __restrict__ degcount,
                          const u32* __restrict__ mbits, const u16* __restrict__ Vimg,
                          float* __restrict__ partial)
{
  const int slot = blockIdx.z;
  const u32 cnt = *degcount;
  if (slot >= (int)cnt) return;
  const int ksec = blockIdx.x, bh = blockIdx.y;
  const int q = (int)deglist[slot];
  const int t = threadIdx.x;
  const int d = t & 127, kc = t >> 7;          // kc in {0,1}: chunks 0-3 / 4-7
  const u16* vb = Vimg + ((long)bh * 32 + ksec) * 8192 + d * 64;
  const u32 w0 = mbits[q * 64 + ksec * 2];
  const u32 w1 = mbits[q * 64 + ksec * 2 + 1];
  float a = 0.f;
#pragma unroll
  for (int i = 0; i < 4; ++i) {
    int c = kc * 4 + i;                        // chunk 0..7, covers k = ksec*64 + c*8 ..+7
    u32 bits = ((kc == 0) ? (w0 >> (c * 8)) : (w1 >> ((c - 4) * 8))) & 0xffu;
    u16x8 v = *(const u16x8*)(&vb[(c ^ (d & 7)) << 3]);
#pragma unroll
    for (int j = 0; j < 8; ++j)
      a += ((bits >> j) & 1u) ? 0.f : bf2f(v[j]);
  }
  __shared__ float tmp[2][128];
  tmp[kc][d] = a;
  __syncthreads();
  if (t < 128)
    partial[(((long)slot * BH_ + bh) * 128 + d) * 32 + ksec] = tmp[0][d] + tmp[1][d];
}

// ---------------------------------------------------------------------------
// Kernel 5b: combine partials -> Ob. Grid (8 slots, 32 bh), 128 threads.
// ---------------------------------------------------------------------------
__global__ __launch_bounds__(128)
void fixup_combine_kernel(const u32* __restrict__ deglist, const u32* __restrict__ degcount,
                          const float* __restrict__ cnt0inv, const float* __restrict__ partial,
                          u16* __restrict__ Ob)
{
  const int slot = blockIdx.x;
  const u32 cnt = *degcount;
  if (slot >= (int)cnt) return;
  const int bh = blockIdx.y;
  const int q = (int)deglist[slot];
  const int d = threadIdx.x;
  const float* p = partial + (((long)slot * BH_ + bh) * 128 + d) * 32;
  float s = 0.f;
#pragma unroll
  for (int i = 0; i < 8; ++i) {
    f32x4 v = *(const f32x4*)(&p[i * 4]);
    s += (v[0] + v[1]) + (v[2] + v[3]);
  }
  Ob[((long)bh * T_ + q) * 128 + d] = f2bf(s * cnt0inv[q]);
}

// ---------------------------------------------------------------------------
// Kernel 5c: fallback for slots >= 8 (pathological masks; never runs for the
// bench mask — all blocks exit after two loads). Same math, serial per row.
// ---------------------------------------------------------------------------
__global__ __launch_bounds__(256)
void fixup_slow_kernel(const u32* __restrict__ deglist, const u32* __restrict__ degcount,
                       const float* __restrict__ cnt0inv, const u32* __restrict__ mbits,
                       const u16* __restrict__ Vimg, u16* __restrict__ Ob)
{
  const u32 cnt = *degcount;
  const int bh = blockIdx.y;
  const int d = threadIdx.x & 127, half = threadIdx.x >> 7;
  __shared__ float tmp[2][128];
  const u16* vb = Vimg + (long)bh * 32 * 8192;
  for (u32 idx = 8 + blockIdx.x; idx < cnt; idx += gridDim.x) {
    const int q = (int)deglist[idx];
    const float inv = cnt0inv[q];
    float a = 0.f;
#pragma unroll 16
    for (int i = 0; i < 128; ++i) {
      int k0 = half * 1024 + i * 8;
      u32 w = mbits[q * 64 + (k0 >> 5)];
      u32 bits = (w >> (k0 & 31)) & 0xffu;
      int kt = k0 >> 6, kk = k0 & 63;
      u16x8 v = *(const u16x8*)(&vb[(long)kt * 8192 + d * 64 + (((kk >> 3) ^ (d & 7)) << 3)]);
#pragma unroll
      for (int j = 0; j < 8; ++j)
        a += ((bits >> j) & 1u) ? 0.f : bf2f(v[j]);
    }
    tmp[half][d] = a;
    __syncthreads();
    if (half == 0)
      Ob[((long)bh * T_ + q) * 128 + d] = f2bf((tmp[0][d] + tmp[1][d]) * inv);
    __syncthreads();
  }
}

// ---------------------------------------------------------------------------
// Kernel 6: output projection. out[8192 x 128] = A[8192 x 1024] * Wu + bu,
// A[m][h*128+d] = O[(b,h,t,d)]. 32-row tiles, K chunk = one head (128).
// ---------------------------------------------------------------------------
__global__ __launch_bounds__(256)
void outproj_kernel(const u16* __restrict__ Ob, const u16* __restrict__ WuT,
                    const float* __restrict__ bu, float* __restrict__ out)
{
  __shared__ __align__(16) u16 As[32 * 128];
  __shared__ __align__(16) u16 Bs[128 * 128];
  const int tid = threadIdx.x;
  const int m0 = blockIdx.x * 32;
  const int wave = tid >> 6, lane = tid & 63;
  const int lr = lane & 15, lg = lane >> 4;
  f32x4 acc[2][2];
#pragma unroll
  for (int a = 0; a < 2; ++a)
#pragma unroll
    for (int b = 0; b < 2; ++b) acc[a][b] = (f32x4){0.f, 0.f, 0.f, 0.f};
  for (int kc = 0; kc < 8; ++kc) {
    __syncthreads();
#pragma unroll
    for (int i = 0; i < 2; ++i) {
      int c = tid + 256 * i;               // 512 chunks
      int row = c >> 4, d0 = (c & 15) * 8;
      int m = m0 + row, bb = m >> 11, t = m & 2047;
      *(u16x8*)(&As[row * 128 + ((((d0 >> 3)) ^ (row & 15)) << 3)]) =
          *(const u16x8*)(&Ob[((long)(bb * H_ + kc) * T_ + t) * 128 + d0]);
    }
#pragma unroll
    for (int i = 0; i < 8; ++i) {
      int c = tid + 256 * i;               // 2048 chunks
      int row = c >> 4, d0 = (c & 15) * 8;
      *(u16x8*)(&Bs[row * 128 + ((((d0 >> 3)) ^ (row & 15)) << 3)]) =
          *(const u16x8*)(&WuT[row * 1024 + kc * 128 + d0]);
    }
    __syncthreads();
#pragma unroll
    for (int ks = 0; ks < 4; ++ks) {
      bf16x8 af[2], bf2[2];
#pragma unroll
      for (int mt = 0; mt < 2; ++mt) {
        int row = mt * 16 + lr, chunk = lg + ks * 4;
        af[mt] = *(const bf16x8*)(&As[row * 128 + ((chunk ^ (row & 15)) << 3)]);
      }
#pragma unroll
      for (int nt = 0; nt < 2; ++nt) {
        int row = wave * 32 + nt * 16 + lr, chunk = lg + ks * 4;
        bf2[nt] = *(const bf16x8*)(&Bs[row * 128 + ((chunk ^ (row & 15)) << 3)]);
      }
#pragma unroll
      for (int mt = 0; mt < 2; ++mt)
#pragma unroll
        for (int nt = 0; nt < 2; ++nt)
          acc[mt][nt] = __builtin_amdgcn_mfma_f32_16x16x32_bf16(af[mt], bf2[nt], acc[mt][nt], 0, 0, 0);
    }
  }
#pragma unroll
  for (int mt = 0; mt < 2; ++mt)
#pragma unroll
    for (int nt = 0; nt < 2; ++nt) {
      int n = wave * 32 + nt * 16 + lr;
      float bias = bu[n];
#pragma unroll
      for (int r = 0; r < 4; ++r) {
        int m = m0 + mt * 16 + lg * 4 + r;
        out[(long)m * 128 + n] = acc[mt][nt][r] + bias;
      }
    }
}

// ---------------------------------------------------------------------------
extern "C" void kernel_launch(void* const* d_in, const int* in_sizes, int n_in,
                              void* d_out, int out_size, void* d_ws, size_t ws_size,
                              hipStream_t stream)
{
  (void)in_sizes; (void)n_in; (void)out_size; (void)ws_size;
  const float* x   = (const float*)d_in[0];
  const int*   msk = (const int*)d_in[1];
  const float* Wq  = (const float*)d_in[2];
  const float* Wk  = (const float*)d_in[3];
  const float* Wv  = (const float*)d_in[4];
  const float* Wu  = (const float*)d_in[5];
  const float* bu  = (const float*)d_in[6];
  float* out = (float*)d_out;

  // workspace layout (bf16 elements unless noted); total ~67.6 MB
  u16* Qb   = (u16*)d_ws;
  u16* Kimg = Qb + (size_t)BH_ * T_ * 128;      // [bh][32][8192] swizzled image
  u16* Vimg = Kimg + (size_t)BH_ * T_ * 128;    // [bh][32][8192] swizzled image
  u16* Obf  = Vimg + (size_t)BH_ * T_ * 128;
  u16* xb   = Obf + (size_t)BH_ * T_ * 128;
  u16* WT   = xb + (size_t)M_ * 128;            // [3072][128]
  u16* WuT  = WT + (size_t)3072 * 128;          // [128][1024]
  u32* mbits   = (u32*)(WuT + (size_t)128 * 1024);
  u32* deglist = mbits + (size_t)2048 * 64;
  u32* degcount = deglist + 2048;
  float* cnt0inv = (float*)(degcount + 1);
  // fixup partials alias Qb: dead after flash_kernel; 8*32*128*32*4 B = 4 MB
  float* partial = (float*)Qb;

  hipMemsetAsync(degcount, 0, sizeof(u32), stream);
  prep_kernel<<<6144, 256, 0, stream>>>(x, Wq, Wk, Wv, Wu, xb, WT, WuT);
  maskprep_kernel<<<512, 256, 0, stream>>>(msk, mbits, deglist, degcount, cnt0inv);
  qkv_kernel<<<dim3(24, 64), 256, 0, stream>>>(xb, WT, Qb, Kimg, Vimg);
  flash_kernel<<<1024, 256, 0, stream>>>(Qb, Kimg, Vimg, mbits, Obf);
  fixup_partial_kernel<<<dim3(32, 32, 8), 256, 0, stream>>>(deglist, degcount, mbits, Vimg, partial);
  fixup_combine_kernel<<<dim3(8, 32), 128, 0, stream>>>(deglist, degcount, cnt0inv, partial, Obf);
  fixup_slow_kernel<<<dim3(32, 32), 256, 0, stream>>>(deglist, degcount, cnt0inv, mbits, Vimg, Obf);
  outproj_kernel<<<256, 256, 0, stream>>>(Obf, WuT, bu, out);
}

// Round 20
// 132.560 us; speedup vs baseline: 1.2093x; 1.1687x over previous
//
#include <hip/hip_runtime.h>
#include <hip/hip_bf16.h>

typedef unsigned short u16;
typedef unsigned int u32;
typedef __attribute__((ext_vector_type(8))) short bf16x8;   // 8 bf16 = 4 VGPR (MFMA A/B frag)
typedef __attribute__((ext_vector_type(4))) float f32x4;    // MFMA C/D frag
typedef __attribute__((ext_vector_type(8))) unsigned short u16x8;
typedef __attribute__((ext_vector_type(2))) unsigned int u32x2;

#define T_ 2048
#define H_ 8
#define BH_ 32
#define M_ 8192
#define SCALE_QK 0.29730177875068026f   // 128^(-0.25), folded into Wq and Wk
#define LOG2E 1.4426950408889634f       // extra factor on Wq -> softmax in exp2 domain

__device__ __forceinline__ u16 f2bf(float f) {
  union { __hip_bfloat16 h; u16 u; } cv; cv.h = __float2bfloat16(f); return cv.u;
}
__device__ __forceinline__ float bf2f(u16 u) {
  union { u16 u; __hip_bfloat16 h; } cv; cv.u = u; return __bfloat162float(cv.h);
}

// K image block (bh,kt): 64x128 tile, elem(kr,d) at kr*128 + (((d>>3)^(kr&15))<<3) + (d&7)
// V image block (bh,kt): 128x64 tile, elem(d,kk) at d*64  + (((kk>>3)^(d&7))<<3)  + (kk&7)
// Both are verbatim images of the flash kernel's swizzled LDS tiles.
// (R16 lesson: V MUST be LDS-staged — direct per-fragment global reads
// overfetch HBM 8.7x; LDS staging is the coalescing mechanism.)

// ---------------------------------------------------------------------------
// Kernel 1 (FUSED prep + maskprep — independent work, one launch):
// blocks 0..6143: x -> bf16; Wq/Wk/Wv -> WT (scales folded; Wq also *log2e);
//                 Wu -> WuT.
// blocks 6144..6655: pack mask rows into bitwords; deglist; cnt0inv.
// ---------------------------------------------------------------------------
__global__ __launch_bounds__(256)
void prep_kernel(const float* __restrict__ x, const float* __restrict__ Wq,
                 const float* __restrict__ Wk, const float* __restrict__ Wv,
                 const float* __restrict__ Wu, const int* __restrict__ mask,
                 u16* __restrict__ xb, u16* __restrict__ WT, u16* __restrict__ WuT,
                 u32* __restrict__ mbits, u32* __restrict__ deglist,
                 u32* __restrict__ degcount, float* __restrict__ cnt0inv)
{
  if (blockIdx.x < 6144) {
    int i = blockIdx.x * 256 + threadIdx.x;
    if (i < M_ * 128) { xb[i] = f2bf(x[i]); return; }
    int j = i - M_ * 128;
    if (j < 3072 * 128) {
      int n = j >> 7, k = j & 127;
      float w;
      if (n < 1024)      w = Wq[k * 1024 + n] * (SCALE_QK * LOG2E);
      else if (n < 2048) w = Wk[k * 1024 + (n - 1024)] * SCALE_QK;
      else               w = Wv[k * 1024 + (n - 2048)];
      WT[j] = f2bf(w);
      return;
    }
    int u = j - 3072 * 128;
    if (u < 128 * 1024) {
      int n = u >> 10, k = u & 1023;
      WuT[u] = f2bf(Wu[k * 128 + n]);
    }
    return;
  }
  // ---- maskprep part: one wave per mask row ----
  int blk = blockIdx.x - 6144;
  int wave = threadIdx.x >> 6, lane = threadIdx.x & 63;
  int q = blk * 4 + wave;
  const int* row = mask + (long)q * 2048;
  unsigned long long anyvis = 0ull;
  int cnt1 = 0;
  for (int it = 0; it < 32; ++it) {
    int k = it * 64 + lane;
    unsigned long long bal = __ballot(row[k] != 0);
    if (lane == 0) {
      mbits[q * 64 + it * 2]     = (u32)bal;
      mbits[q * 64 + it * 2 + 1] = (u32)(bal >> 32);
    }
    cnt1 += __popcll(bal);
    int lim = q - it * 64;                      // visible lane offsets: 0..lim
    if (lim >= 63)      anyvis |= bal;
    else if (lim >= 0)  anyvis |= (bal & ((2ull << lim) - 1ull));
  }
  if (lane == 0) {
    int c0 = 2048 - cnt1;
    cnt0inv[q] = (c0 > 0) ? 1.0f / (float)c0 : 0.0f;
    if (anyvis == 0ull) {
      u32 slot = atomicAdd(degcount, 1u);
      deglist[slot] = (u32)q;
    }
  }
}

// ---------------------------------------------------------------------------
// Kernel 3: QKV projection GEMM. 128x128 tile, K=128, 4 waves, 16x16x32 MFMA.
// All epilogues go through LDS staging -> coalesced u16x8 global stores
// (no scalar global scatter). Q row-major; K,V as swizzled image blocks.
// ---------------------------------------------------------------------------
__global__ __launch_bounds__(256)
void qkv_kernel(const u16* __restrict__ xb, const u16* __restrict__ WT,
                u16* __restrict__ Qb, u16* __restrict__ Kimg, u16* __restrict__ Vimg)
{
  __shared__ __align__(16) u16 As[128 * 128];
  __shared__ __align__(16) u16 Bs[128 * 128];
  const int tid = threadIdx.x;
  const int n0 = blockIdx.x * 128;    // over concat [Wq|Wk|Wv] = 3072 cols
  const int m0 = blockIdx.y * 128;
#pragma unroll
  for (int i = 0; i < 8; ++i) {
    int c = tid + 256 * i;            // 2048 chunks of 8 elems
    int row = c >> 4, d0 = (c & 15) * 8;
    int soff = row * 128 + ((((d0 >> 3)) ^ (row & 15)) << 3);
    *(u16x8*)(&As[soff]) = *(const u16x8*)(&xb[(m0 + row) * 128 + d0]);
    *(u16x8*)(&Bs[soff]) = *(const u16x8*)(&WT[(n0 + row) * 128 + d0]);
  }
  __syncthreads();
  const int wave = tid >> 6, lane = tid & 63;
  const int lr = lane & 15, lg = lane >> 4;
  const int wm = (wave >> 1) * 64, wn = (wave & 1) * 64;
  f32x4 acc[4][4];
#pragma unroll
  for (int a = 0; a < 4; ++a)
#pragma unroll
    for (int b = 0; b < 4; ++b) acc[a][b] = (f32x4){0.f, 0.f, 0.f, 0.f};
#pragma unroll
  for (int ks = 0; ks < 4; ++ks) {
    bf16x8 af[4], bf[4];
#pragma unroll
    for (int mt = 0; mt < 4; ++mt) {
      int row = wm + mt * 16 + lr, chunk = lg + ks * 4;
      af[mt] = *(const bf16x8*)(&As[row * 128 + ((chunk ^ (row & 15)) << 3)]);
    }
#pragma unroll
    for (int nt = 0; nt < 4; ++nt) {
      int row = wn + nt * 16 + lr, chunk = lg + ks * 4;
      bf[nt] = *(const bf16x8*)(&Bs[row * 128 + ((chunk ^ (row & 15)) << 3)]);
    }
#pragma unroll
    for (int mt = 0; mt < 4; ++mt)
#pragma unroll
      for (int nt = 0; nt < 4; ++nt)
        acc[mt][nt] = __builtin_amdgcn_mfma_f32_16x16x32_bf16(af[mt], bf[nt], acc[mt][nt], 0, 0, 0);
  }
  const int mat = n0 >> 10;
  const int hh = (n0 & 1023) >> 7;
  const int bb = m0 >> 11;
  const long bhb = (long)(bb * H_ + hh);
  __syncthreads();                       // done reading As/Bs; reuse As
  if (mat != 2) {
    // stage C tile [tl][d] (chunk-swizzled), then vectorized stores
#pragma unroll
    for (int mt = 0; mt < 4; ++mt)
#pragma unroll
      for (int nt = 0; nt < 4; ++nt)
#pragma unroll
        for (int r = 0; r < 4; ++r) {
          int tl = wm + mt * 16 + lg * 4 + r;
          int d  = wn + nt * 16 + lr;
          As[tl * 128 + ((((d >> 3)) ^ (tl & 15)) << 3) + (d & 7)] = f2bf(acc[mt][nt][r]);
        }
    __syncthreads();
    if (mat == 0) {
#pragma unroll
      for (int i = 0; i < 8; ++i) {
        int c = tid + 256 * i;
        int row = c >> 4, d0 = (c & 15) * 8;
        u16x8 v = *(const u16x8*)(&As[row * 128 + ((((d0 >> 3)) ^ (row & 15)) << 3)]);
        *(u16x8*)(&Qb[(bhb * T_ + ((m0 + row) & 2047)) * 128 + d0]) = v;
      }
    } else {
#pragma unroll
      for (int i = 0; i < 8; ++i) {
        int c = tid + 256 * i;
        int row = c >> 4, d0 = (c & 15) * 8;
        u16x8 v = *(const u16x8*)(&As[row * 128 + ((((d0 >> 3)) ^ (row & 15)) << 3)]);
        int t = (m0 + row) & 2047;
        int kt = t >> 6, kr = t & 63;
        *(u16x8*)(&Kimg[(bhb * 32 + kt) * 8192 + kr * 128 + ((((d0 >> 3)) ^ (kr & 15)) << 3)]) = v;
      }
    }
  } else {
    // transpose V tile in LDS (reuse As), then u16x8 stores into V image blocks
    u16* TT = As;
#pragma unroll
    for (int mt = 0; mt < 4; ++mt)
#pragma unroll
      for (int nt = 0; nt < 4; ++nt)
#pragma unroll
        for (int r = 0; r < 4; ++r) {
          int tl = wm + mt * 16 + lg * 4 + r;   // local t 0..127
          int d  = wn + nt * 16 + lr;
          TT[d * 128 + ((((tl >> 3)) ^ (d & 15)) << 3) + (tl & 7)] = f2bf(acc[mt][nt][r]);
        }
    __syncthreads();
    const int tg0 = m0 & 2047;
#pragma unroll
    for (int i = 0; i < 8; ++i) {
      int c = tid + 256 * i;
      int d = c >> 4, t0 = (c & 15) * 8;
      u16x8 v = *(const u16x8*)(&TT[d * 128 + ((((t0 >> 3)) ^ (d & 15)) << 3)]);
      int tg = tg0 + t0;
      int kt = tg >> 6, kk = tg & 63;
      *(u16x8*)(&Vimg[(bhb * 32 + kt) * 8192 + d * 64 + (((kk >> 3) ^ (d & 7)) << 3)]) = v;
    }
  }
}

// ---------------------------------------------------------------------------
// Kernel 4: flash attention (R17 structure — proven best: 81.0 us).
// SWAPPED operands, 16x16x32 MFMA, reg-staged software pipeline,
// quad-balanced static grid, exp2-domain softmax, T13 defer-max (THR=8).
// LDS 40960 B; VGPR 84 -> __launch_bounds__(256,3). (R19 lesson: forcing
// (256,4) squeezes VGPR to 64 and spills ~36 MB — keep 3.)
// ---------------------------------------------------------------------------
__global__ __launch_bounds__(256, 3)
void flash_kernel(const u16* __restrict__ Qb, const u16* __restrict__ Kimg,
                  const u16* __restrict__ Vimg, const u32* __restrict__ mbits,
                  u16* __restrict__ Ob)
{
  __shared__ __align__(16) u16 Ks[64 * 128];
  __shared__ __align__(16) u16 VTs[128 * 64];
  __shared__ __align__(16) u16 Ps[4][16 * 64];
  const int tid = threadIdx.x;
  // quad-balanced qt permutation: g=b>>5, a=g&7, quad=g>>3
  const int g = blockIdx.x >> 5;
  const int a_ = g & 7, quad = g >> 3;
  const int qt = (quad == 0) ? (31 - a_) : (quad == 1) ? (8 + a_)
               : (quad == 2) ? (23 - a_) : a_;
  const int bh = blockIdx.x & 31;
  const int q0 = qt * 64;
  const int wave = tid >> 6, lane = tid & 63;
  const int lr = lane & 15, lg = lane >> 4;
  const long base = (long)bh * T_ * 128;       // Q/O rows
  const long iblk = (long)bh * 32;             // image block index base
  const int ldsoff = wave * 2048 + lane * 8;   // this thread's staging offset (u16)
  const int qrl = wave * 16 + lr;              // this lane's local q-row (0..63)
  const int swz = (lr & 7) << 1;               // Ps chunk swizzle (bit0-preserving)

  bf16x8 qf[4];                                // Q[q0+qrl][.] as B-operand
  {
    const u16* qrow = Qb + base + (long)(q0 + qrl) * 128;
#pragma unroll
    for (int ks = 0; ks < 4; ++ks)
      qf[ks] = *(const bf16x8*)(&qrow[lg * 8 + ks * 32]);
  }
  f32x4 acc[8];                                // O^T: row=d, col=qrow=lr
#pragma unroll
  for (int i = 0; i < 8; ++i) acc[i] = (f32x4){0.f, 0.f, 0.f, 0.f};
  float mrun = -__builtin_inff(), lrun = 0.f;

  // prefetch tile 0 into registers
  u16x8 kreg[4], vreg[4];
  {
    const u16* ks0 = Kimg + iblk * 8192 + ldsoff;
    const u16* vs0 = Vimg + iblk * 8192 + ldsoff;
#pragma unroll
    for (int i = 0; i < 4; ++i) {
      kreg[i] = *(const u16x8*)(ks0 + i * 512);
      vreg[i] = *(const u16x8*)(vs0 + i * 512);
    }
  }

  for (int kt = 0; kt <= qt; ++kt) {
    __syncthreads();                       // A: prev-tile readers done
#pragma unroll
    for (int i = 0; i < 4; ++i) {          // regs -> LDS (linear image layout)
      *(u16x8*)(&Ks[ldsoff + i * 512]) = kreg[i];
      *(u16x8*)(&VTs[ldsoff + i * 512]) = vreg[i];
    }
    __syncthreads();                       // B: drains ds_writes; vm queue empty
    // issue next tile's K/V loads — they complete during the compute below
    if (kt < qt) {
      const u16* ksn = Kimg + (iblk + kt + 1) * 8192 + ldsoff;
      const u16* vsn = Vimg + (iblk + kt + 1) * 8192 + ldsoff;
#pragma unroll
      for (int i = 0; i < 4; ++i) {
        kreg[i] = *(const u16x8*)(ksn + i * 512);
        vreg[i] = *(const u16x8*)(vsn + i * 512);
      }
    }
    // mask words for this lane's q-row (used after QK; latency hidden)
    u32 mw0, mw1;
    {
      const u32* mp = &mbits[(q0 + qrl) * 64 + kt * 2];
      mw0 = mp[0]; mw1 = mp[1];
    }

    // S^T = K Q^T : lane holds S[qrow=lr][key=ft*16+lg*4+r]
    f32x4 s[4];
    __builtin_amdgcn_s_setprio(1);
#pragma unroll
    for (int ft = 0; ft < 4; ++ft) {
      f32x4 sa = (f32x4){0.f, 0.f, 0.f, 0.f};
#pragma unroll
      for (int ks = 0; ks < 4; ++ks) {
        int kr = ft * 16 + lr, chunk = lg + ks * 4;
        bf16x8 kf = *(const bf16x8*)(&Ks[kr * 128 + ((chunk ^ (kr & 15)) << 3)]);
        sa = __builtin_amdgcn_mfma_f32_16x16x32_bf16(kf, qf[ks], sa, 0, 0, 0);
      }
      s[ft] = sa;
    }
    __builtin_amdgcn_s_setprio(0);
    // masking (key = ft*16 + lg*4 + r, all in-lane)
    const bool diag = (kt == qt);
#pragma unroll
    for (int ft = 0; ft < 4; ++ft) {
      u32 w = (ft & 2) ? mw1 : mw0;
      int kbase = ft * 16 + lg * 4;
      int sh = ((ft & 1) << 4) + lg * 4;
#pragma unroll
      for (int r = 0; r < 4; ++r) {
        bool vis = (w >> (sh + r)) & 1u;
        if (diag && (kbase + r) > qrl) vis = false;
        if (!vis) s[ft][r] = -__builtin_inff();
      }
    }
    // online softmax (exp2 domain) with defer-max (T13, THR=8)
    float t0 = fmaxf(fmaxf(s[0][0], s[0][1]), fmaxf(s[0][2], s[0][3]));
    float t1 = fmaxf(fmaxf(s[1][0], s[1][1]), fmaxf(s[1][2], s[1][3]));
    float t2 = fmaxf(fmaxf(s[2][0], s[2][1]), fmaxf(s[2][2], s[2][3]));
    float t3 = fmaxf(fmaxf(s[3][0], s[3][1]), fmaxf(s[3][2], s[3][3]));
    float tm = fmaxf(fmaxf(t0, t1), fmaxf(t2, t3));
    tm = fmaxf(tm, __shfl_xor(tm, 16));
    tm = fmaxf(tm, __shfl_xor(tm, 32));
    // skip if EVERY q-row's tile-max is within THR of its running max
    // (fresh rows: mrun=-inf -> tm-mrun=+inf/NaN -> no skip)
    const bool skip = __all(tm - mrun <= 8.0f);
    float fac = 1.0f;
    float msafe = (mrun == -__builtin_inff()) ? 0.f : mrun;
    if (!skip) {
      float mnew = fmaxf(mrun, tm);
      msafe = (mnew == -__builtin_inff()) ? 0.f : mnew;
      fac = __builtin_amdgcn_exp2f(mrun - msafe);
      mrun = mnew;
    }
    float rs = 0.f;
#pragma unroll
    for (int ft = 0; ft < 4; ++ft) {
      float p0 = __builtin_amdgcn_exp2f(s[ft][0] - msafe);
      float p1 = __builtin_amdgcn_exp2f(s[ft][1] - msafe);
      float p2 = __builtin_amdgcn_exp2f(s[ft][2] - msafe);
      float p3 = __builtin_amdgcn_exp2f(s[ft][3] - msafe);
      s[ft][0] = p0; s[ft][1] = p1; s[ft][2] = p2; s[ft][3] = p3;
      rs += (p0 + p1) + (p2 + p3);
    }
    rs += __shfl_xor(rs, 16);
    rs += __shfl_xor(rs, 32);
    lrun = lrun * fac + rs;
    if (!skip) {
#pragma unroll
      for (int nt = 0; nt < 8; ++nt)
#pragma unroll
        for (int r = 0; r < 4; ++r) acc[nt][r] *= fac;
    }
    // P-pack: 4 keys per ft are consecutive -> one b64 write each
#pragma unroll
    for (int ft = 0; ft < 4; ++ft) {
      u16 h0 = f2bf(s[ft][0]), h1 = f2bf(s[ft][1]);
      u16 h2 = f2bf(s[ft][2]), h3 = f2bf(s[ft][3]);
      u32x2 pw; pw[0] = (u32)h0 | ((u32)h1 << 16); pw[1] = (u32)h2 | ((u32)h3 << 16);
      int ch4 = (ft * 4 + lg) ^ swz;
      *(u32x2*)(&Ps[wave][lr * 64 + ch4 * 4]) = pw;
    }
    bf16x8 pa[2];                          // P[qrow=lr][k=s2*32+lg*8+j] (B-operand)
#pragma unroll
    for (int s2 = 0; s2 < 2; ++s2) {
      int ch4b = (s2 * 8 + lg * 2) ^ swz;
      pa[s2] = *(const bf16x8*)(&Ps[wave][lr * 64 + ch4b * 4]);
    }
    __builtin_amdgcn_s_setprio(1);
#pragma unroll
    for (int nt = 0; nt < 8; ++nt)
#pragma unroll
      for (int s2 = 0; s2 < 2; ++s2) {
        int d = nt * 16 + lr, chunk = lg + s2 * 4;
        bf16x8 vf = *(const bf16x8*)(&VTs[d * 64 + ((chunk ^ (d & 7)) << 3)]);
        acc[nt] = __builtin_amdgcn_mfma_f32_16x16x32_bf16(vf, pa[s2], acc[nt], 0, 0, 0);
      }
    __builtin_amdgcn_s_setprio(0);
  }
  const float inv = (lrun > 0.f) ? 1.f / lrun : 0.f;
  const long orow = base + (long)(q0 + qrl) * 128;
#pragma unroll
  for (int nt = 0; nt < 8; ++nt) {
    u16 h0 = f2bf(acc[nt][0] * inv), h1 = f2bf(acc[nt][1] * inv);
    u16 h2 = f2bf(acc[nt][2] * inv), h3 = f2bf(acc[nt][3] * inv);
    u32x2 ow; ow[0] = (u32)h0 | ((u32)h1 << 16); ow[1] = (u32)h2 | ((u32)h3 << 16);
    *(u32x2*)(&Ob[orow + nt * 16 + lg * 4]) = ow;
  }
}

// ---------------------------------------------------------------------------
// Kernel 5a: degenerate-row partial sums. Block = (ksec, bh, slot):
// sums V[bh, ksec*64 .. +63, d] over mask==0 -> partial[slot][bh][d][ksec].
// partial aliases Qb (dead after flash). No memset/atomics needed.
// ---------------------------------------------------------------------------
__global__ __launch_bounds__(256)
void fixup_partial_kernel(const u32* __restrict__ deglist, const u32* __restrict__ degcount,
                          const u32* __restrict__ mbits, const u16* __restrict__ Vimg,
                          float* __restrict__ partial)
{
  const int slot = blockIdx.z;
  const u32 cnt = *degcount;
  if (slot >= (int)cnt) return;
  const int ksec = blockIdx.x, bh = blockIdx.y;
  const int q = (int)deglist[slot];
  const int t = threadIdx.x;
  const int d = t & 127, kc = t >> 7;          // kc in {0,1}: chunks 0-3 / 4-7
  const u16* vb = Vimg + ((long)bh * 32 + ksec) * 8192 + d * 64;
  const u32 w0 = mbits[q * 64 + ksec * 2];
  const u32 w1 = mbits[q * 64 + ksec * 2 + 1];
  float a = 0.f;
#pragma unroll
  for (int i = 0; i < 4; ++i) {
    int c = kc * 4 + i;                        // chunk 0..7, covers k = ksec*64 + c*8 ..+7
    u32 bits = ((kc == 0) ? (w0 >> (c * 8)) : (w1 >> ((c - 4) * 8))) & 0xffu;
    u16x8 v = *(const u16x8*)(&vb[(c ^ (d & 7)) << 3]);
#pragma unroll
    for (int j = 0; j < 8; ++j)
      a += ((bits >> j) & 1u) ? 0.f : bf2f(v[j]);
  }
  __shared__ float tmp[2][128];
  tmp[kc][d] = a;
  __syncthreads();
  if (t < 128)
    partial[(((long)slot * BH_ + bh) * 128 + d) * 32 + ksec] = tmp[0][d] + tmp[1][d];
}

// ---------------------------------------------------------------------------
// Kernel 5b: combine partials -> Ob. Grid (8 slots, 32 bh), 128 threads.
// ---------------------------------------------------------------------------
__global__ __launch_bounds__(128)
void fixup_combine_kernel(const u32* __restrict__ deglist, const u32* __restrict__ degcount,
                          const float* __restrict__ cnt0inv, const float* __restrict__ partial,
                          u16* __restrict__ Ob)
{
  const int slot = blockIdx.x;
  const u32 cnt = *degcount;
  if (slot >= (int)cnt) return;
  const int bh = blockIdx.y;
  const int q = (int)deglist[slot];
  const int d = threadIdx.x;
  const float* p = partial + (((long)slot * BH_ + bh) * 128 + d) * 32;
  float s = 0.f;
#pragma unroll
  for (int i = 0; i < 8; ++i) {
    f32x4 v = *(const f32x4*)(&p[i * 4]);
    s += (v[0] + v[1]) + (v[2] + v[3]);
  }
  Ob[((long)bh * T_ + q) * 128 + d] = f2bf(s * cnt0inv[q]);
}

// ---------------------------------------------------------------------------
// Kernel 5c: fallback for slots >= 8 (pathological masks; never runs for the
// bench mask — all blocks exit after two loads). Same math, serial per row.
// ---------------------------------------------------------------------------
__global__ __launch_bounds__(256)
void fixup_slow_kernel(const u32* __restrict__ deglist, const u32* __restrict__ degcount,
                       const float* __restrict__ cnt0inv, const u32* __restrict__ mbits,
                       const u16* __restrict__ Vimg, u16* __restrict__ Ob)
{
  const u32 cnt = *degcount;
  const int bh = blockIdx.y;
  const int d = threadIdx.x & 127, half = threadIdx.x >> 7;
  __shared__ float tmp[2][128];
  const u16* vb = Vimg + (long)bh * 32 * 8192;
  for (u32 idx = 8 + blockIdx.x; idx < cnt; idx += gridDim.x) {
    const int q = (int)deglist[idx];
    const float inv = cnt0inv[q];
    float a = 0.f;
#pragma unroll 16
    for (int i = 0; i < 128; ++i) {
      int k0 = half * 1024 + i * 8;
      u32 w = mbits[q * 64 + (k0 >> 5)];
      u32 bits = (w >> (k0 & 31)) & 0xffu;
      int kt = k0 >> 6, kk = k0 & 63;
      u16x8 v = *(const u16x8*)(&vb[(long)kt * 8192 + d * 64 + (((kk >> 3) ^ (d & 7)) << 3)]);
#pragma unroll
      for (int j = 0; j < 8; ++j)
        a += ((bits >> j) & 1u) ? 0.f : bf2f(v[j]);
    }
    tmp[half][d] = a;
    __syncthreads();
    if (half == 0)
      Ob[((long)bh * T_ + q) * 128 + d] = f2bf((tmp[0][d] + tmp[1][d]) * inv);
    __syncthreads();
  }
}

// ---------------------------------------------------------------------------
// Kernel 6: output projection. out[8192 x 128] = A[8192 x 1024] * Wu + bu,
// A[m][h*128+d] = O[(b,h,t,d)]. 32-row tiles, K chunk = one head (128).
// ---------------------------------------------------------------------------
__global__ __launch_bounds__(256)
void outproj_kernel(const u16* __restrict__ Ob, const u16* __restrict__ WuT,
                    const float* __restrict__ bu, float* __restrict__ out)
{
  __shared__ __align__(16) u16 As[32 * 128];
  __shared__ __align__(16) u16 Bs[128 * 128];
  const int tid = threadIdx.x;
  const int m0 = blockIdx.x * 32;
  const int wave = tid >> 6, lane = tid & 63;
  const int lr = lane & 15, lg = lane >> 4;
  f32x4 acc[2][2];
#pragma unroll
  for (int a = 0; a < 2; ++a)
#pragma unroll
    for (int b = 0; b < 2; ++b) acc[a][b] = (f32x4){0.f, 0.f, 0.f, 0.f};
  for (int kc = 0; kc < 8; ++kc) {
    __syncthreads();
#pragma unroll
    for (int i = 0; i < 2; ++i) {
      int c = tid + 256 * i;               // 512 chunks
      int row = c >> 4, d0 = (c & 15) * 8;
      int m = m0 + row, bb = m >> 11, t = m & 2047;
      *(u16x8*)(&As[row * 128 + ((((d0 >> 3)) ^ (row & 15)) << 3)]) =
          *(const u16x8*)(&Ob[((long)(bb * H_ + kc) * T_ + t) * 128 + d0]);
    }
#pragma unroll
    for (int i = 0; i < 8; ++i) {
      int c = tid + 256 * i;               // 2048 chunks
      int row = c >> 4, d0 = (c & 15) * 8;
      *(u16x8*)(&Bs[row * 128 + ((((d0 >> 3)) ^ (row & 15)) << 3)]) =
          *(const u16x8*)(&WuT[row * 1024 + kc * 128 + d0]);
    }
    __syncthreads();
#pragma unroll
    for (int ks = 0; ks < 4; ++ks) {
      bf16x8 af[2], bf2[2];
#pragma unroll
      for (int mt = 0; mt < 2; ++mt) {
        int row = mt * 16 + lr, chunk = lg + ks * 4;
        af[mt] = *(const bf16x8*)(&As[row * 128 + ((chunk ^ (row & 15)) << 3)]);
      }
#pragma unroll
      for (int nt = 0; nt < 2; ++nt) {
        int row = wave * 32 + nt * 16 + lr, chunk = lg + ks * 4;
        bf2[nt] = *(const bf16x8*)(&Bs[row * 128 + ((chunk ^ (row & 15)) << 3)]);
      }
#pragma unroll
      for (int mt = 0; mt < 2; ++mt)
#pragma unroll
        for (int nt = 0; nt < 2; ++nt)
          acc[mt][nt] = __builtin_amdgcn_mfma_f32_16x16x32_bf16(af[mt], bf2[nt], acc[mt][nt], 0, 0, 0);
    }
  }
#pragma unroll
  for (int mt = 0; mt < 2; ++mt)
#pragma unroll
    for (int nt = 0; nt < 2; ++nt) {
      int n = wave * 32 + nt * 16 + lr;
      float bias = bu[n];
#pragma unroll
      for (int r = 0; r < 4; ++r) {
        int m = m0 + mt * 16 + lg * 4 + r;
        out[(long)m * 128 + n] = acc[mt][nt][r] + bias;
      }
    }
}

// ---------------------------------------------------------------------------
extern "C" void kernel_launch(void* const* d_in, const int* in_sizes, int n_in,
                              void* d_out, int out_size, void* d_ws, size_t ws_size,
                              hipStream_t stream)
{
  (void)in_sizes; (void)n_in; (void)out_size; (void)ws_size;
  const float* x   = (const float*)d_in[0];
  const int*   msk = (const int*)d_in[1];
  const float* Wq  = (const float*)d_in[2];
  const float* Wk  = (const float*)d_in[3];
  const float* Wv  = (const float*)d_in[4];
  const float* Wu  = (const float*)d_in[5];
  const float* bu  = (const float*)d_in[6];
  float* out = (float*)d_out;

  // workspace layout (bf16 elements unless noted); total ~67.6 MB
  u16* Qb   = (u16*)d_ws;
  u16* Kimg = Qb + (size_t)BH_ * T_ * 128;      // [bh][32][8192] swizzled image
  u16* Vimg = Kimg + (size_t)BH_ * T_ * 128;    // [bh][32][8192] swizzled image
  u16* Obf  = Vimg + (size_t)BH_ * T_ * 128;
  u16* xb   = Obf + (size_t)BH_ * T_ * 128;
  u16* WT   = xb + (size_t)M_ * 128;            // [3072][128]
  u16* WuT  = WT + (size_t)3072 * 128;          // [128][1024]
  u32* mbits   = (u32*)(WuT + (size_t)128 * 1024);
  u32* deglist = mbits + (size_t)2048 * 64;
  u32* degcount = deglist + 2048;
  float* cnt0inv = (float*)(degcount + 1);
  // fixup partials alias Qb: dead after flash_kernel; 8*32*128*32*4 B = 4 MB
  float* partial = (float*)Qb;

  hipMemsetAsync(degcount, 0, sizeof(u32), stream);
  prep_kernel<<<6656, 256, 0, stream>>>(x, Wq, Wk, Wv, Wu, msk, xb, WT, WuT,
                                        mbits, deglist, degcount, cnt0inv);
  qkv_kernel<<<dim3(24, 64), 256, 0, stream>>>(xb, WT, Qb, Kimg, Vimg);
  flash_kernel<<<1024, 256, 0, stream>>>(Qb, Kimg, Vimg, mbits, Obf);
  fixup_partial_kernel<<<dim3(32, 32, 8), 256, 0, stream>>>(deglist, degcount, mbits, Vimg, partial);
  fixup_combine_kernel<<<dim3(8, 32), 128, 0, stream>>>(deglist, degcount, cnt0inv, partial, Obf);
  fixup_slow_kernel<<<dim3(32, 32), 256, 0, stream>>>(deglist, degcount, cnt0inv, mbits, Vimg, Obf);
  outproj_kernel<<<256, 256, 0, stream>>>(Obf, WuT, bu, out);
}